// Round 4
// baseline (497.021 us; speedup 1.0000x reference)
//
#include <hip/hip_runtime.h>
#include <hip/hip_bf16.h>

// GNN: h = x@We^T + be; 2x { h = relu(segsum(h[col],row) @ W^T + b) };
// out = relu(mean(h,1) @ Wc1^T + bc1) @ Wc2^T + bc2   (scalar fp32)
//
// Restructure: relu((A h) W^T + b) == relu(A (h W^T) + b)  (A = sparse adj).
// R10: kill the remaining intra-tile serialization. R9 measured 5550
// cyc/tile = MFMA 2211 + LDS ~2050 + VALU ~1060 nearly SERIAL (MfmaUtil
// 37%). Cause: (a) af[] register reuse for A rows 64-127 creates a WAR
// hazard between MFMA cluster 2 and the reload ds_reads (full lgkm drain
// between clusters); (b) read bursts at tile start leave MFMA idle.
// Fix: dedicated afB[4] regs -> ALL 24 fragment ds_reads issue upfront,
// ordered by first use; first MFMA waits only its 12 deps, the other 12
// drain under clusters 1-2 via compiler-counted lgkmcnt. One setprio
// pair around the whole 32-MFMA block. A-stage before reads, B-stage
// right after -> whole tile of MFMA covers the L2 transfer before the
// boundary vmcnt(0) (the loop's only barrier).
// NOTE: SQ_LDS_BANK_CONFLICT == exactly 4x ds_read_b128 count (R6-R9) ==
// intrinsic b128 overhead, NOT a real conflict. Read pattern hits all 32
// banks evenly (8 accesses each = the floor). Don't chase it.
//   - 256x256 tile, 512 threads, 8 waves (2Mx4N), BK=128, double-buffered
//     LDS (128 KiB), MX-scaled fp8 mfma_scale_f32_16x16x128_f8f6f4.
//   - LDS: natural 128B row stride, slot-XOR swizzle (16B slot ^= row&7);
//     inverse swizzle folded into per-lane GLOBAL source addresses of
//     global_load_lds (linear LDS dest), swizzled ds_read offsets.
//   - XCD swizzle: 4x8 sub-rectangle of tiles per XCD (12 MB panel set).

#define N_NODES 4096
#define IN_DIM_ 512
#define HID_ 4096
#define NEDGE 65536

typedef float f32x4 __attribute__((ext_vector_type(4)));
typedef float f32x2 __attribute__((ext_vector_type(2)));
typedef unsigned short u16x8 __attribute__((ext_vector_type(8)));
typedef int i32x8 __attribute__((ext_vector_type(8)));

#define ACT_SCALE 8.0f     // activations fp8 = 8 x true
#define W_SCALE 256.0f     // weights fp8 = 256 x true
#define G_SCALE 8.0f       // g fp8 = 8 x true
// gemm acc = 2048 x true; fp8-store multiplier = 8/2048
#define G_STORE_MUL (8.0f / 2048.0f)

__device__ __forceinline__ unsigned short f2bf(float f) {
  unsigned u = __float_as_uint(f);
  return (unsigned short)((u + 0x7fffu + ((u >> 16) & 1u)) >> 16);  // RNE
}
__device__ __forceinline__ float bf2f(unsigned short h) {
  return __uint_as_float((unsigned)h << 16);
}
__device__ __forceinline__ unsigned char f2fp8(float f) {
  int w = __builtin_amdgcn_cvt_pk_fp8_f32(f, f, 0, false);  // OCP e4m3
  return (unsigned char)(w & 0xff);
}
// decode 4 fp8 bytes of w into acc[0..3] (+=)
__device__ __forceinline__ void fp8x4_acc(int w, float* acc) {
  f32x2 lo = __builtin_amdgcn_cvt_pk_f32_fp8(w, false);
  f32x2 hi = __builtin_amdgcn_cvt_pk_f32_fp8(w, true);
  acc[0] += lo[0]; acc[1] += lo[1]; acc[2] += hi[0]; acc[3] += hi[1];
}

// ---------------- fp32 -> fp8 e4m3 (x scale), 8 elems/thread ----------------
__global__ __launch_bounds__(256) void cvt_fp8(const float* __restrict__ in,
                                               unsigned char* __restrict__ out,
                                               int n, float scale) {
  int i = (blockIdx.x * 256 + threadIdx.x) * 8;
  if (i >= n) return;
  const float4 a = *(const float4*)(in + i);
  const float4 b = *(const float4*)(in + i + 4);
  int w0 = __builtin_amdgcn_cvt_pk_fp8_f32(a.x * scale, a.y * scale, 0, false);
  w0 = __builtin_amdgcn_cvt_pk_fp8_f32(a.z * scale, a.w * scale, w0, true);
  int w1 = __builtin_amdgcn_cvt_pk_fp8_f32(b.x * scale, b.y * scale, 0, false);
  w1 = __builtin_amdgcn_cvt_pk_fp8_f32(b.z * scale, b.w * scale, w1, true);
  *(int2*)(out + i) = make_int2(w0, w1);
}

// ---------------- CSR build ----------------
__global__ __launch_bounds__(256) void zero_i32(int* __restrict__ p, int n) {
  int i = blockIdx.x * 256 + threadIdx.x;
  if (i < n) p[i] = 0;
}

__global__ __launch_bounds__(256) void hist_rows(const int* __restrict__ row,
                                                 int* __restrict__ counts) {
  int e = blockIdx.x * 256 + threadIdx.x;
  if (e < NEDGE) atomicAdd(&counts[row[e]], 1);
}

// exclusive scan of counts[4096] -> starts[4097]; single block of 1024 threads
__global__ __launch_bounds__(1024) void scan4096(const int* __restrict__ counts,
                                                 int* __restrict__ starts) {
  __shared__ int sa[1024], sb[1024];
  const int t = threadIdx.x;
  const int c0 = counts[t * 4], c1 = counts[t * 4 + 1],
            c2 = counts[t * 4 + 2], c3 = counts[t * 4 + 3];
  const int local = c0 + c1 + c2 + c3;
  sa[t] = local;
  __syncthreads();
  int* src = sa; int* dst = sb;
  for (int off = 1; off < 1024; off <<= 1) {
    int v = src[t];
    if (t >= off) v += src[t - off];
    dst[t] = v;
    __syncthreads();
    int* tmp = src; src = dst; dst = tmp;
  }
  const int excl = (t == 0) ? 0 : src[t - 1];
  starts[t * 4]     = excl;
  starts[t * 4 + 1] = excl + c0;
  starts[t * 4 + 2] = excl + c0 + c1;
  starts[t * 4 + 3] = excl + c0 + c1 + c2;
  if (t == 1023) starts[4096] = excl + local;
}

__global__ __launch_bounds__(256) void fill_adj(const int* __restrict__ row,
                                                const int* __restrict__ col,
                                                const int* __restrict__ starts,
                                                int* __restrict__ cursor,
                                                int* __restrict__ adj) {
  int e = blockIdx.x * 256 + threadIdx.x;
  if (e >= NEDGE) return;
  int r = row[e];
  int p = atomicAdd(&cursor[r], 1);
  adj[starts[r] + p] = col[e];
}

// ---- MX fp8 GEMM: C_fp8 = fp8(mul*(A@B^T) [+ ACT_SCALE*bias]) ----
// 256x256 tile, BK=128, 8 waves each 128x64, 1 barrier per K-tile.
#define GLDS(gp, lp)                                                       \
  __builtin_amdgcn_global_load_lds(                                        \
      (const __attribute__((address_space(1))) void*)(gp),                 \
      (__attribute__((address_space(3))) void*)(lp), 16, 0, 0)

__global__ __launch_bounds__(512, 2) void gemm_mx(
    const unsigned char* __restrict__ A, const unsigned char* __restrict__ B,
    unsigned char* __restrict__ C, int N, int K,
    const float* __restrict__ bias, float mul) {
  __shared__ unsigned char lds[131072];   // [A dbuf 2x32K][B dbuf 2x32K]
  const int t = threadIdx.x;
  // XCD swizzle: XCD x owns a 4(bm) x 8(bn) sub-rectangle of the 16x16 tile
  // grid (bijective for nwg=256). 32 co-resident blocks/XCD share
  // 4 A-panels + 8 B-panels; per-K-step working set 384 KB << 4 MB L2.
  const int w = blockIdx.x;
  const int xcd = w & 7, j = w >> 3;
  const int bm = ((xcd & 3) * 4 + (j & 3)) * 256;
  const int bn = ((xcd >> 2) * 8 + (j >> 2)) * 256;
  const int wave = t >> 6, lane = t & 63;
  const int wm = (wave >> 2) * 128, wn = (wave & 3) * 64;
  const int m16 = lane & 15, quad = lane >> 4;

  f32x4 acc[8][4] = {};

  // staging: thread t, inst i -> LDS linear byte (i*64 + t/8)*128 + (t%8)*16.
  // LDS slot s of row r must hold global k-slot s^(r&7)  (read-side swizzle),
  // so pre-XOR the per-lane GLOBAL source slot; LDS dest stays linear.
  const int rS = t >> 3;                       // 0..63
  const int sS = ((t & 7) ^ (rS & 7)) << 4;    // pre-swizzled k-slot byte
  const unsigned char* Ag = A + (size_t)(bm + rS) * K + sS;
  const unsigned char* Bg = B + (size_t)(bn + rS) * K + sS;
  const size_t rstep = (size_t)64 * K;         // +64 rows per staging inst
  unsigned char* Als = lds;
  unsigned char* Bls = lds + 65536;
  const int sd = t * 16;

  // read-side swizzled 16B-slot offsets for k = quad*32 .. +31
  const int o0 = ((quad << 1) ^ (lane & 7)) << 4;
  const int o1 = o0 ^ 16;

  const int KT = K >> 7;

#define STAGE_A(i, kb, dst) GLDS(Ag + (kb) + (size_t)(i) * rstep, (dst) + (i) * 8192 + sd)
#define STAGE_B(i, kb, dst) GLDS(Bg + (kb) + (size_t)(i) * rstep, (dst) + (i) * 8192 + sd)

#define LDFRAG(dst, base, row)                                             \
  {                                                                        \
    const unsigned char* _p = (base) + (row) * 128;                        \
    const int4 _lo = *(const int4*)(_p + o0);                              \
    const int4 _hi = *(const int4*)(_p + o1);                              \
    dst[0] = _lo.x; dst[1] = _lo.y; dst[2] = _lo.z; dst[3] = _lo.w;        \
    dst[4] = _hi.x; dst[5] = _hi.y; dst[6] = _hi.z; dst[7] = _hi.w;        \
  }

#define MFMA(r, c, afr, bfr)                                               \
  acc[r][c] = __builtin_amdgcn_mfma_scale_f32_16x16x128_f8f6f4(            \
      afr, bfr, acc[r][c], 0, 0, 0, 0x7f7f7f7f, 0, 0x7f7f7f7f)

  // prologue: stage tile 0 into buf 0 (only exposed wait of the loop)
  STAGE_A(0, 0, Als); STAGE_A(1, 0, Als); STAGE_A(2, 0, Als); STAGE_A(3, 0, Als);
  STAGE_B(0, 0, Bls); STAGE_B(1, 0, Bls); STAGE_B(2, 0, Bls); STAGE_B(3, 0, Bls);
  asm volatile("s_waitcnt vmcnt(0)" ::: "memory");
  __builtin_amdgcn_s_barrier();

  // dedicated register sets: afA rows 0-63, afB rows 64-127 of the wave
  // tile -> no WAR hazard, all 24 ds_reads issue upfront per tile.
  i32x8 afA[4], afB[4], bf01[2], bf23[2];

  for (int tt = 0; tt < KT; ++tt) {
    unsigned char* Ab = Als + (tt & 1) * 32768;
    unsigned char* Bb = Bls + (tt & 1) * 32768;
    unsigned char* An = Als + ((tt + 1) & 1) * 32768;
    unsigned char* Bn = Bls + ((tt + 1) & 1) * 32768;
    const int kbn = (tt + 1) << 7;
    const bool more = (tt + 1) < KT;

    if (more) {
      STAGE_A(0, kbn, An); STAGE_A(1, kbn, An);
      STAGE_A(2, kbn, An); STAGE_A(3, kbn, An);
    }
    // all 24 fragment reads, ordered by first use; compiler-counted
    // lgkmcnt lets cluster 1 start after its 12 deps while the rest
    // drain under the MFMAs.
    LDFRAG(afA[0], Ab, wm + m16);
    LDFRAG(afA[1], Ab, wm + 16 + m16);
    LDFRAG(afA[2], Ab, wm + 32 + m16);
    LDFRAG(afA[3], Ab, wm + 48 + m16);
    LDFRAG(bf01[0], Bb, wn + m16);
    LDFRAG(bf01[1], Bb, wn + 16 + m16);
    LDFRAG(bf23[0], Bb, wn + 32 + m16);
    LDFRAG(bf23[1], Bb, wn + 48 + m16);
    LDFRAG(afB[0], Ab, wm + 64 + m16);
    LDFRAG(afB[1], Ab, wm + 80 + m16);
    LDFRAG(afB[2], Ab, wm + 96 + m16);
    LDFRAG(afB[3], Ab, wm + 112 + m16);
    if (more) {
      STAGE_B(0, kbn, Bn); STAGE_B(1, kbn, Bn);
      STAGE_B(2, kbn, Bn); STAGE_B(3, kbn, Bn);
    }
    __builtin_amdgcn_s_setprio(1);
    MFMA(0, 0, afA[0], bf01[0]); MFMA(0, 1, afA[0], bf01[1]);
    MFMA(1, 0, afA[1], bf01[0]); MFMA(1, 1, afA[1], bf01[1]);
    MFMA(2, 0, afA[2], bf01[0]); MFMA(2, 1, afA[2], bf01[1]);
    MFMA(3, 0, afA[3], bf01[0]); MFMA(3, 1, afA[3], bf01[1]);
    MFMA(0, 2, afA[0], bf23[0]); MFMA(0, 3, afA[0], bf23[1]);
    MFMA(1, 2, afA[1], bf23[0]); MFMA(1, 3, afA[1], bf23[1]);
    MFMA(2, 2, afA[2], bf23[0]); MFMA(2, 3, afA[2], bf23[1]);
    MFMA(3, 2, afA[3], bf23[0]); MFMA(3, 3, afA[3], bf23[1]);
    MFMA(4, 0, afB[0], bf01[0]); MFMA(4, 1, afB[0], bf01[1]);
    MFMA(5, 0, afB[1], bf01[0]); MFMA(5, 1, afB[1], bf01[1]);
    MFMA(6, 0, afB[2], bf01[0]); MFMA(6, 1, afB[2], bf01[1]);
    MFMA(7, 0, afB[3], bf01[0]); MFMA(7, 1, afB[3], bf01[1]);
    MFMA(4, 2, afB[0], bf23[0]); MFMA(4, 3, afB[0], bf23[1]);
    MFMA(5, 2, afB[1], bf23[0]); MFMA(5, 3, afB[1], bf23[1]);
    MFMA(6, 2, afB[2], bf23[0]); MFMA(6, 3, afB[2], bf23[1]);
    MFMA(7, 2, afB[3], bf23[0]); MFMA(7, 3, afB[3], bf23[1]);
    __builtin_amdgcn_s_setprio(0);
    if (more) {
      // tile-boundary: t+1's staging (issued a whole tile of MFMA ago)
      // must have landed; all buf-cur reads were consumed above. The
      // loop's ONLY barrier.
      asm volatile("s_waitcnt vmcnt(0)" ::: "memory");
      __builtin_amdgcn_sched_barrier(0);
      __builtin_amdgcn_s_barrier();
    }
  }

#undef MFMA
#undef LDFRAG
#undef STAGE_A
#undef STAGE_B

  // C/D layout (16x16 family, shape-determined): col=lane&15, row=quad*4+reg
#pragma unroll
  for (int r = 0; r < 8; ++r) {
#pragma unroll
    for (int c = 0; c < 4; ++c) {
      const int row0 = bm + wm + r * 16 + quad * 4;
      const int col = bn + wn + c * 16 + m16;
      const float bv = bias ? ACT_SCALE * bias[col] : 0.0f;
#pragma unroll
      for (int i = 0; i < 4; ++i) {
        C[(size_t)(row0 + i) * N + col] = f2fp8(acc[r][c][i] * mul + bv);
      }
    }
  }
}
#undef GLDS

// ---- aggregation (fp8 g in): h = relu(sum g[c]/G_SCALE + b) -> fp8 x ACT ----
__global__ __launch_bounds__(256) void aggr_f8out(
    const unsigned char* __restrict__ g, const int* __restrict__ starts,
    const int* __restrict__ adj, const float* __restrict__ bias,
    unsigned char* __restrict__ hout) {
  const int node = blockIdx.y;
  const int f0 = blockIdx.x * 2048 + threadIdx.x * 8;
  float acc[8] = {0, 0, 0, 0, 0, 0, 0, 0};
  const int s = starts[node], e = starts[node + 1];
  int j = s;
  for (; j + 4 <= e; j += 4) {
    const int c0 = adj[j], c1 = adj[j + 1], c2 = adj[j + 2], c3 = adj[j + 3];
    int2 v0 = *(const int2*)(g + (size_t)c0 * HID_ + f0);
    int2 v1 = *(const int2*)(g + (size_t)c1 * HID_ + f0);
    int2 v2 = *(const int2*)(g + (size_t)c2 * HID_ + f0);
    int2 v3 = *(const int2*)(g + (size_t)c3 * HID_ + f0);
    fp8x4_acc(v0.x, acc);     fp8x4_acc(v0.y, acc + 4);
    fp8x4_acc(v1.x, acc);     fp8x4_acc(v1.y, acc + 4);
    fp8x4_acc(v2.x, acc);     fp8x4_acc(v2.y, acc + 4);
    fp8x4_acc(v3.x, acc);     fp8x4_acc(v3.y, acc + 4);
  }
  for (; j < e; ++j) {
    int2 v = *(const int2*)(g + (size_t)adj[j] * HID_ + f0);
    fp8x4_acc(v.x, acc);      fp8x4_acc(v.y, acc + 4);
  }
  const float4 b0 = *(const float4*)(bias + f0);
  const float4 b1 = *(const float4*)(bias + f0 + 4);
  const float bb[8] = {b0.x, b0.y, b0.z, b0.w, b1.x, b1.y, b1.z, b1.w};
  float v[8];
#pragma unroll
  for (int i = 0; i < 8; ++i)
    v[i] = ACT_SCALE * fmaxf(acc[i] * (1.0f / G_SCALE) + bb[i], 0.0f);
  int w0 = __builtin_amdgcn_cvt_pk_fp8_f32(v[0], v[1], 0, false);
  w0 = __builtin_amdgcn_cvt_pk_fp8_f32(v[2], v[3], w0, true);
  int w1 = __builtin_amdgcn_cvt_pk_fp8_f32(v[4], v[5], 0, false);
  w1 = __builtin_amdgcn_cvt_pk_fp8_f32(v[6], v[7], w1, true);
  *(int2*)(hout + (size_t)node * HID_ + f0) = make_int2(w0, w1);
}

// ---- aggregation variant emitting bf16 (final layer) ----
__global__ __launch_bounds__(256) void aggr_bf16out(
    const unsigned char* __restrict__ g, const int* __restrict__ starts,
    const int* __restrict__ adj, const float* __restrict__ bias,
    unsigned short* __restrict__ hout) {
  const int node = blockIdx.y;
  const int f0 = blockIdx.x * 2048 + threadIdx.x * 8;
  float acc[8] = {0, 0, 0, 0, 0, 0, 0, 0};
  const int s = starts[node], e = starts[node + 1];
  int j = s;
  for (; j + 4 <= e; j += 4) {
    const int c0 = adj[j], c1 = adj[j + 1], c2 = adj[j + 2], c3 = adj[j + 3];
    int2 v0 = *(const int2*)(g + (size_t)c0 * HID_ + f0);
    int2 v1 = *(const int2*)(g + (size_t)c1 * HID_ + f0);
    int2 v2 = *(const int2*)(g + (size_t)c2 * HID_ + f0);
    int2 v3 = *(const int2*)(g + (size_t)c3 * HID_ + f0);
    fp8x4_acc(v0.x, acc);     fp8x4_acc(v0.y, acc + 4);
    fp8x4_acc(v1.x, acc);     fp8x4_acc(v1.y, acc + 4);
    fp8x4_acc(v2.x, acc);     fp8x4_acc(v2.y, acc + 4);
    fp8x4_acc(v3.x, acc);     fp8x4_acc(v3.y, acc + 4);
  }
  for (; j < e; ++j) {
    int2 v = *(const int2*)(g + (size_t)adj[j] * HID_ + f0);
    fp8x4_acc(v.x, acc);      fp8x4_acc(v.y, acc + 4);
  }
  const float4 b0 = *(const float4*)(bias + f0);
  const float4 b1 = *(const float4*)(bias + f0 + 4);
  const float bb[8] = {b0.x, b0.y, b0.z, b0.w, b1.x, b1.y, b1.z, b1.w};
  u16x8 r;
#pragma unroll
  for (int i = 0; i < 8; ++i)
    r[i] = f2bf(fmaxf(acc[i] * (1.0f / G_SCALE) + bb[i], 0.0f));
  *(u16x8*)(hout + (size_t)node * HID_ + f0) = r;
}

// ---------------- hm[row] = mean(h[row,:]) ----------------
__global__ __launch_bounds__(256) void row_mean(const unsigned short* __restrict__ h,
                                                float* __restrict__ hm) {
  const int row = blockIdx.x, t = threadIdx.x;
  const u16x8* p = (const u16x8*)(h + (size_t)row * HID_);
  u16x8 v1 = p[t], v2 = p[t + 256];
  float s = 0.f;
#pragma unroll
  for (int i = 0; i < 8; ++i) s += bf2f(v1[i]) + bf2f(v2[i]);
  for (int off = 32; off > 0; off >>= 1) s += __shfl_down(s, off);
  __shared__ float ws[4];
  if ((t & 63) == 0) ws[t >> 6] = s;
  __syncthreads();
  if (t == 0) hm[row] = (ws[0] + ws[1] + ws[2] + ws[3]) * (1.0f / (float)HID_);
}

// ---------------- z[j] = relu(Wc1[j,:].hm + bc1[j]), one wave per j ----------------
__global__ __launch_bounds__(256) void clf1(const float* __restrict__ Wc1,
                                            const float* __restrict__ bc1,
                                            const float* __restrict__ hm,
                                            float* __restrict__ z) {
  const int wave = threadIdx.x >> 6, lane = threadIdx.x & 63;
  const int j = blockIdx.x * 4 + wave;
  const float* w = Wc1 + (size_t)j * HID_;
  float s = 0.f;
  for (int i = lane; i < HID_; i += 64) s += w[i] * hm[i];
  for (int off = 32; off > 0; off >>= 1) s += __shfl_down(s, off);
  if (lane == 0) z[j] = fmaxf(s + bc1[j], 0.0f);
}

// ---------------- out = Wc2.z + bc2 ----------------
__global__ __launch_bounds__(256) void clf2(const float* __restrict__ Wc2,
                                            const float* __restrict__ bc2,
                                            const float* __restrict__ z,
                                            float* __restrict__ out) {
  const int t = threadIdx.x;
  float s = 0.f;
  for (int i = t; i < HID_ / 2; i += 256) s += z[i] * Wc2[i];
  for (int off = 32; off > 0; off >>= 1) s += __shfl_down(s, off);
  __shared__ float ws[4];
  if ((t & 63) == 0) ws[t >> 6] = s;
  __syncthreads();
  if (t == 0) out[0] = ws[0] + ws[1] + ws[2] + ws[3] + bc2[0];
}

extern "C" void kernel_launch(void* const* d_in, const int* in_sizes, int n_in,
                              void* d_out, int out_size, void* d_ws, size_t ws_size,
                              hipStream_t stream) {
  (void)in_sizes; (void)n_in; (void)out_size; (void)ws_size;
  const float* x       = (const float*)d_in[0];
  const int*   edge    = (const int*)d_in[1];
  const int*   row     = edge;
  const int*   col     = edge + NEDGE;
  const float* W_embed = (const float*)d_in[2];
  const float* b_embed = (const float*)d_in[3];
  const float* W1      = (const float*)d_in[4];
  const float* b1      = (const float*)d_in[5];
  const float* W2      = (const float*)d_in[6];
  const float* b2      = (const float*)d_in[7];
  const float* Wc1     = (const float*)d_in[8];
  const float* bc1     = (const float*)d_in[9];
  const float* Wc2     = (const float*)d_in[10];
  const float* bc2     = (const float*)d_in[11];
  float* out = (float*)d_out;

  char* ws = (char*)d_ws;
  size_t off = 0;
  auto alloc = [&](size_t bytes) {
    char* p = ws + off;
    off += (bytes + 255) & ~(size_t)255;
    return p;
  };
  unsigned char*  xf8  = (unsigned char*)alloc((size_t)N_NODES * IN_DIM_);
  unsigned char*  wef8 = (unsigned char*)alloc((size_t)HID_ * IN_DIM_);
  unsigned char*  w1f8 = (unsigned char*)alloc((size_t)HID_ * HID_);
  unsigned char*  w2f8 = (unsigned char*)alloc((size_t)HID_ * HID_);
  unsigned char*  h0f8 = (unsigned char*)alloc((size_t)N_NODES * HID_);
  unsigned char*  h1f8 = (unsigned char*)alloc((size_t)N_NODES * HID_);
  unsigned char*  g    = (unsigned char*)alloc((size_t)N_NODES * HID_);
  unsigned short* h2   = (unsigned short*)alloc((size_t)N_NODES * HID_ * 2);
  int* counts = (int*)alloc(N_NODES * 4);
  int* cursor = (int*)alloc(N_NODES * 4);
  int* starts = (int*)alloc((N_NODES + 1) * 4);
  int* adj    = (int*)alloc(NEDGE * 4);
  float* hm   = (float*)alloc(N_NODES * 4);
  float* z    = (float*)alloc((HID_ / 2) * 4);

  // CSR build (ws is re-poisoned each call -> must zero)
  zero_i32<<<16, 256, 0, stream>>>(counts, N_NODES);
  zero_i32<<<16, 256, 0, stream>>>(cursor, N_NODES);
  hist_rows<<<NEDGE / 256, 256, 0, stream>>>(row, counts);
  scan4096<<<1, 1024, 0, stream>>>(counts, starts);
  fill_adj<<<NEDGE / 256, 256, 0, stream>>>(row, col, starts, cursor, adj);

  // fp8 conversions (natural order; staging does the slot shuffle)
  cvt_fp8<<<(N_NODES * IN_DIM_ / 8) / 256, 256, 0, stream>>>(x, xf8, N_NODES * IN_DIM_, ACT_SCALE);
  cvt_fp8<<<(HID_ * IN_DIM_ / 8) / 256, 256, 0, stream>>>(W_embed, wef8, HID_ * IN_DIM_, W_SCALE);
  cvt_fp8<<<(HID_ * HID_ / 8) / 256, 256, 0, stream>>>(W1, w1f8, HID_ * HID_, W_SCALE);
  cvt_fp8<<<(HID_ * HID_ / 8) / 256, 256, 0, stream>>>(W2, w2f8, HID_ * HID_, W_SCALE);

  // embed: h0 = fp8(8 * (x @ We^T + be))
  gemm_mx<<<256, 512, 0, stream>>>(xf8, wef8, h0f8, HID_, IN_DIM_,
                                   b_embed, G_STORE_MUL);
  // layer 1: g = h0 @ W1^T ; h1 = fp8(8 * relu(A g + b1))
  gemm_mx<<<256, 512, 0, stream>>>(h0f8, w1f8, g, HID_, HID_,
                                   nullptr, G_STORE_MUL);
  aggr_f8out<<<dim3(2, N_NODES), 256, 0, stream>>>(g, starts, adj, b1, h1f8);
  // layer 2: g = h1 @ W2^T ; h2 = relu(A g + b2) (bf16)
  gemm_mx<<<256, 512, 0, stream>>>(h1f8, w2f8, g, HID_, HID_,
                                   nullptr, G_STORE_MUL);
  aggr_bf16out<<<dim3(2, N_NODES), 256, 0, stream>>>(g, starts, adj, b2, h2);
  // classifier tail
  row_mean<<<N_NODES, 256, 0, stream>>>(h2, hm);
  clf1<<<(HID_ / 2) / 4, 256, 0, stream>>>(Wc1, bc1, hm, z);
  clf2<<<1, 256, 0, stream>>>(Wc2, bc2, z, out);
}

// Round 5
// 444.143 us; speedup vs baseline: 1.1191x; 1.1191x over previous
//
#include <hip/hip_runtime.h>
#include <hip/hip_bf16.h>

// GNN: h = x@We^T + be; 2x { h = relu(segsum(h[col],row) @ W^T + b) };
// out = relu(mean(h,1) @ Wc1^T + bc1) @ Wc2^T + bc2   (scalar fp32)
//
// Restructure: relu((A h) W^T + b) == relu(A (h W^T) + b)  (A = sparse adj).
// R11: GEMM reverted to R9 (74 us, MfmaUtil 37%) -- R10's dedicated afB[4]
// regs spilled: WRITE_SIZE 16.4->22.5 MB + FETCH +3 MB = ~9 MB scratch
// traffic, VALUBusy +9.5pts at constant VGPR_Count=128 (overflow went to
// scratch, not more regs). LESSON: 12 live i32x8 frags + 128-reg acc is
// over budget; R9's mid-stream af reload is the right tradeoff.
// This round's lever is the periphery (~290 us of 458 is non-GEMM):
//   - aggr_bf16out + row_mean fused into aggr_mean: h2 (33 MB bf16) was
//     only consumed as a row mean -> reduce in-kernel (wave shuffle +
//     1 float atomicAdd per block), never materialize h2. -66 MB traffic.
//   - 4x cvt_fp8 -> 1x cvt_all (range dispatch); 2x zero_i32 -> 1 pass
//     over counts|cursor|hm (made adjacent). 17 -> 12 launches.
// GEMM notes (R9): 1 barrier per K-tile; reads+staging upfront, compiler
// -counted lgkmcnt pipelines reads under MFMAs; boundary vmcnt(0) covered
// by a full tile of MFMA. SQ_LDS_BANK_CONFLICT == 4x ds_read_b128 count
// (intrinsic b128 overhead, m134), NOT a real conflict -- don't chase it.
//   - 256x256 tile, 512 threads, 8 waves (2Mx4N), BK=128, double-buffered
//     LDS (128 KiB), MX-scaled fp8 mfma_scale_f32_16x16x128_f8f6f4.
//   - LDS: natural 128B row stride, slot-XOR swizzle (16B slot ^= row&7);
//     inverse swizzle folded into per-lane GLOBAL source addresses of
//     global_load_lds (linear LDS dest), swizzled ds_read offsets.
//   - XCD swizzle: 4x8 sub-rectangle of tiles per XCD (12 MB panel set).

#define N_NODES 4096
#define IN_DIM_ 512
#define HID_ 4096
#define NEDGE 65536

typedef float f32x4 __attribute__((ext_vector_type(4)));
typedef float f32x2 __attribute__((ext_vector_type(2)));
typedef unsigned short u16x8 __attribute__((ext_vector_type(8)));
typedef int i32x8 __attribute__((ext_vector_type(8)));

#define ACT_SCALE 8.0f     // activations fp8 = 8 x true
#define W_SCALE 256.0f     // weights fp8 = 256 x true
#define G_SCALE 8.0f       // g fp8 = 8 x true
// gemm acc = 2048 x true; fp8-store multiplier = 8/2048
#define G_STORE_MUL (8.0f / 2048.0f)

__device__ __forceinline__ unsigned short f2bf(float f) {
  unsigned u = __float_as_uint(f);
  return (unsigned short)((u + 0x7fffu + ((u >> 16) & 1u)) >> 16);  // RNE
}
__device__ __forceinline__ float bf2f(unsigned short h) {
  return __uint_as_float((unsigned)h << 16);
}
__device__ __forceinline__ unsigned char f2fp8(float f) {
  int w = __builtin_amdgcn_cvt_pk_fp8_f32(f, f, 0, false);  // OCP e4m3
  return (unsigned char)(w & 0xff);
}
// decode 4 fp8 bytes of w into acc[0..3] (+=)
__device__ __forceinline__ void fp8x4_acc(int w, float* acc) {
  f32x2 lo = __builtin_amdgcn_cvt_pk_f32_fp8(w, false);
  f32x2 hi = __builtin_amdgcn_cvt_pk_f32_fp8(w, true);
  acc[0] += lo[0]; acc[1] += lo[1]; acc[2] += hi[0]; acc[3] += hi[1];
}

// ------- fused fp32 -> fp8 e4m3 for x|We|W1|W2 (range dispatch) -------
#define CVT_E0 ((long)N_NODES * IN_DIM_)                  // x:  2097152
#define CVT_E1 (CVT_E0 + (long)HID_ * IN_DIM_)            // We: 4194304
#define CVT_E2 (CVT_E1 + (long)HID_ * HID_)               // W1: 20971520
#define CVT_E3 (CVT_E2 + (long)HID_ * HID_)               // W2: 37748736
__global__ __launch_bounds__(256) void cvt_all(
    const float* __restrict__ x, const float* __restrict__ We,
    const float* __restrict__ W1, const float* __restrict__ W2,
    unsigned char* __restrict__ xf8, unsigned char* __restrict__ wef8,
    unsigned char* __restrict__ w1f8, unsigned char* __restrict__ w2f8) {
  long i = ((long)blockIdx.x * 256 + threadIdx.x) * 8;
  const float* src; unsigned char* dst; float sc; long o;
  if (i < CVT_E0)      { src = x;  dst = xf8;  sc = ACT_SCALE; o = i; }
  else if (i < CVT_E1) { src = We; dst = wef8; sc = W_SCALE; o = i - CVT_E0; }
  else if (i < CVT_E2) { src = W1; dst = w1f8; sc = W_SCALE; o = i - CVT_E1; }
  else                 { src = W2; dst = w2f8; sc = W_SCALE; o = i - CVT_E2; }
  const float4 a = *(const float4*)(src + o);
  const float4 b = *(const float4*)(src + o + 4);
  int w0 = __builtin_amdgcn_cvt_pk_fp8_f32(a.x * sc, a.y * sc, 0, false);
  w0 = __builtin_amdgcn_cvt_pk_fp8_f32(a.z * sc, a.w * sc, w0, true);
  int w1 = __builtin_amdgcn_cvt_pk_fp8_f32(b.x * sc, b.y * sc, 0, false);
  w1 = __builtin_amdgcn_cvt_pk_fp8_f32(b.z * sc, b.w * sc, w1, true);
  *(int2*)(dst + o) = make_int2(w0, w1);
}

// ---------------- CSR build ----------------
__global__ __launch_bounds__(256) void zero_i32(int* __restrict__ p, int n) {
  int i = blockIdx.x * 256 + threadIdx.x;
  if (i < n) p[i] = 0;
}

__global__ __launch_bounds__(256) void hist_rows(const int* __restrict__ row,
                                                 int* __restrict__ counts) {
  int e = blockIdx.x * 256 + threadIdx.x;
  if (e < NEDGE) atomicAdd(&counts[row[e]], 1);
}

// exclusive scan of counts[4096] -> starts[4097]; single block of 1024 threads
__global__ __launch_bounds__(1024) void scan4096(const int* __restrict__ counts,
                                                 int* __restrict__ starts) {
  __shared__ int sa[1024], sb[1024];
  const int t = threadIdx.x;
  const int c0 = counts[t * 4], c1 = counts[t * 4 + 1],
            c2 = counts[t * 4 + 2], c3 = counts[t * 4 + 3];
  const int local = c0 + c1 + c2 + c3;
  sa[t] = local;
  __syncthreads();
  int* src = sa; int* dst = sb;
  for (int off = 1; off < 1024; off <<= 1) {
    int v = src[t];
    if (t >= off) v += src[t - off];
    dst[t] = v;
    __syncthreads();
    int* tmp = src; src = dst; dst = tmp;
  }
  const int excl = (t == 0) ? 0 : src[t - 1];
  starts[t * 4]     = excl;
  starts[t * 4 + 1] = excl + c0;
  starts[t * 4 + 2] = excl + c0 + c1;
  starts[t * 4 + 3] = excl + c0 + c1 + c2;
  if (t == 1023) starts[4096] = excl + local;
}

__global__ __launch_bounds__(256) void fill_adj(const int* __restrict__ row,
                                                const int* __restrict__ col,
                                                const int* __restrict__ starts,
                                                int* __restrict__ cursor,
                                                int* __restrict__ adj) {
  int e = blockIdx.x * 256 + threadIdx.x;
  if (e >= NEDGE) return;
  int r = row[e];
  int p = atomicAdd(&cursor[r], 1);
  adj[starts[r] + p] = col[e];
}

// ---- MX fp8 GEMM: C_fp8 = fp8(mul*(A@B^T) [+ ACT_SCALE*bias]) ----
// 256x256 tile, BK=128, 8 waves each 128x64, 1 barrier per K-tile. (R9)
#define GLDS(gp, lp)                                                       \
  __builtin_amdgcn_global_load_lds(                                        \
      (const __attribute__((address_space(1))) void*)(gp),                 \
      (__attribute__((address_space(3))) void*)(lp), 16, 0, 0)

__global__ __launch_bounds__(512, 2) void gemm_mx(
    const unsigned char* __restrict__ A, const unsigned char* __restrict__ B,
    unsigned char* __restrict__ C, int N, int K,
    const float* __restrict__ bias, float mul) {
  __shared__ unsigned char lds[131072];   // [A dbuf 2x32K][B dbuf 2x32K]
  const int t = threadIdx.x;
  // XCD swizzle: XCD x owns a 4(bm) x 8(bn) sub-rectangle of the 16x16 tile
  // grid (bijective for nwg=256). 32 co-resident blocks/XCD share
  // 4 A-panels + 8 B-panels; per-K-step working set 384 KB << 4 MB L2.
  const int w = blockIdx.x;
  const int xcd = w & 7, j = w >> 3;
  const int bm = ((xcd & 3) * 4 + (j & 3)) * 256;
  const int bn = ((xcd >> 2) * 8 + (j >> 2)) * 256;
  const int wave = t >> 6, lane = t & 63;
  const int wm = (wave >> 2) * 128, wn = (wave & 3) * 64;
  const int m16 = lane & 15, quad = lane >> 4;

  f32x4 acc[8][4] = {};

  // staging: thread t, inst i -> LDS linear byte (i*64 + t/8)*128 + (t%8)*16.
  // LDS slot s of row r must hold global k-slot s^(r&7)  (read-side swizzle),
  // so pre-XOR the per-lane GLOBAL source slot; LDS dest stays linear.
  const int rS = t >> 3;                       // 0..63
  const int sS = ((t & 7) ^ (rS & 7)) << 4;    // pre-swizzled k-slot byte
  const unsigned char* Ag = A + (size_t)(bm + rS) * K + sS;
  const unsigned char* Bg = B + (size_t)(bn + rS) * K + sS;
  const size_t rstep = (size_t)64 * K;         // +64 rows per staging inst
  unsigned char* Als = lds;
  unsigned char* Bls = lds + 65536;
  const int sd = t * 16;

  // read-side swizzled 16B-slot offsets for k = quad*32 .. +31
  const int o0 = ((quad << 1) ^ (lane & 7)) << 4;
  const int o1 = o0 ^ 16;

  const int KT = K >> 7;

#define STAGE_A(i, kb, dst) GLDS(Ag + (kb) + (size_t)(i) * rstep, (dst) + (i) * 8192 + sd)
#define STAGE_B(i, kb, dst) GLDS(Bg + (kb) + (size_t)(i) * rstep, (dst) + (i) * 8192 + sd)

#define LDFRAG(dst, base, row)                                             \
  {                                                                        \
    const unsigned char* _p = (base) + (row) * 128;                        \
    const int4 _lo = *(const int4*)(_p + o0);                              \
    const int4 _hi = *(const int4*)(_p + o1);                              \
    dst[0] = _lo.x; dst[1] = _lo.y; dst[2] = _lo.z; dst[3] = _lo.w;        \
    dst[4] = _hi.x; dst[5] = _hi.y; dst[6] = _hi.z; dst[7] = _hi.w;        \
  }

#define MFMA(r, c, afr, bfr)                                               \
  acc[r][c] = __builtin_amdgcn_mfma_scale_f32_16x16x128_f8f6f4(            \
      afr, bfr, acc[r][c], 0, 0, 0, 0x7f7f7f7f, 0, 0x7f7f7f7f)

  // prologue: stage tile 0 into buf 0 (only exposed wait of the loop)
  STAGE_A(0, 0, Als); STAGE_A(1, 0, Als); STAGE_A(2, 0, Als); STAGE_A(3, 0, Als);
  STAGE_B(0, 0, Bls); STAGE_B(1, 0, Bls); STAGE_B(2, 0, Bls); STAGE_B(3, 0, Bls);
  asm volatile("s_waitcnt vmcnt(0)" ::: "memory");
  __builtin_amdgcn_s_barrier();

  i32x8 af[4], bf01[2], bf23[2];

  for (int tt = 0; tt < KT; ++tt) {
    unsigned char* Ab = Als + (tt & 1) * 32768;
    unsigned char* Bb = Bls + (tt & 1) * 32768;
    unsigned char* An = Als + ((tt + 1) & 1) * 32768;
    unsigned char* Bn = Bls + ((tt + 1) & 1) * 32768;
    const int kbn = (tt + 1) << 7;
    const bool more = (tt + 1) < KT;

    // Issue all M0-3 + B fragment reads (16 ds_read in flight), then the
    // next-tile A staging; MFMA clusters follow with compiler-counted
    // lgkmcnt waits -- reads for later clusters stay in flight under
    // earlier clusters' MFMAs. No intra-tile barriers: buf-cur reads and
    // buf-nxt staging writes cannot collide.
    LDFRAG(af[0], Ab, wm + m16);
    LDFRAG(af[1], Ab, wm + 16 + m16);
    LDFRAG(af[2], Ab, wm + 32 + m16);
    LDFRAG(af[3], Ab, wm + 48 + m16);
    LDFRAG(bf01[0], Bb, wn + m16);
    LDFRAG(bf01[1], Bb, wn + 16 + m16);
    LDFRAG(bf23[0], Bb, wn + 32 + m16);
    LDFRAG(bf23[1], Bb, wn + 48 + m16);
    if (more) {
      STAGE_A(0, kbn, An); STAGE_A(1, kbn, An);
      STAGE_A(2, kbn, An); STAGE_A(3, kbn, An);
    }
    __builtin_amdgcn_s_setprio(1);
    MFMA(0, 0, af[0], bf01[0]); MFMA(0, 1, af[0], bf01[1]);
    MFMA(1, 0, af[1], bf01[0]); MFMA(1, 1, af[1], bf01[1]);
    MFMA(2, 0, af[2], bf01[0]); MFMA(2, 1, af[2], bf01[1]);
    MFMA(3, 0, af[3], bf01[0]); MFMA(3, 1, af[3], bf01[1]);
    __builtin_amdgcn_s_setprio(0);
    if (more) {
      STAGE_B(0, kbn, Bn); STAGE_B(1, kbn, Bn);
      STAGE_B(2, kbn, Bn); STAGE_B(3, kbn, Bn);
    }
    __builtin_amdgcn_s_setprio(1);
    MFMA(0, 2, af[0], bf23[0]); MFMA(0, 3, af[0], bf23[1]);
    MFMA(1, 2, af[1], bf23[0]); MFMA(1, 3, af[1], bf23[1]);
    MFMA(2, 2, af[2], bf23[0]); MFMA(2, 3, af[2], bf23[1]);
    MFMA(3, 2, af[3], bf23[0]); MFMA(3, 3, af[3], bf23[1]);
    __builtin_amdgcn_s_setprio(0);
    // reload af with rows M4-7 (WAR on af: HW scoreboard orders the LDS
    // writeback after the consuming MFMAs read their operands)
    LDFRAG(af[0], Ab, wm + 64 + m16);
    LDFRAG(af[1], Ab, wm + 80 + m16);
    LDFRAG(af[2], Ab, wm + 96 + m16);
    LDFRAG(af[3], Ab, wm + 112 + m16);
    __builtin_amdgcn_s_setprio(1);
    MFMA(4, 0, af[0], bf01[0]); MFMA(4, 1, af[0], bf01[1]);
    MFMA(5, 0, af[1], bf01[0]); MFMA(5, 1, af[1], bf01[1]);
    MFMA(6, 0, af[2], bf01[0]); MFMA(6, 1, af[2], bf01[1]);
    MFMA(7, 0, af[3], bf01[0]); MFMA(7, 1, af[3], bf01[1]);
    __builtin_amdgcn_s_setprio(0);
    __builtin_amdgcn_s_setprio(1);
    MFMA(4, 2, af[0], bf23[0]); MFMA(4, 3, af[0], bf23[1]);
    MFMA(5, 2, af[1], bf23[0]); MFMA(5, 3, af[1], bf23[1]);
    MFMA(6, 2, af[2], bf23[0]); MFMA(6, 3, af[2], bf23[1]);
    MFMA(7, 2, af[3], bf23[0]); MFMA(7, 3, af[3], bf23[1]);
    __builtin_amdgcn_s_setprio(0);
    if (more) {
      // tile-boundary: t+1's staging (issued ~1-2k cyc ago) must have
      // landed, and all waves' buf-cur reads are drained (every read was
      // consumed by an MFMA above). The loop's ONLY barrier.
      asm volatile("s_waitcnt vmcnt(0)" ::: "memory");
      __builtin_amdgcn_sched_barrier(0);
      __builtin_amdgcn_s_barrier();
    }
  }

#undef MFMA
#undef LDFRAG
#undef STAGE_A
#undef STAGE_B

  // C/D layout (16x16 family, shape-determined): col=lane&15, row=quad*4+reg
#pragma unroll
  for (int r = 0; r < 8; ++r) {
#pragma unroll
    for (int c = 0; c < 4; ++c) {
      const int row0 = bm + wm + r * 16 + quad * 4;
      const int col = bn + wn + c * 16 + m16;
      const float bv = bias ? ACT_SCALE * bias[col] : 0.0f;
#pragma unroll
      for (int i = 0; i < 4; ++i) {
        C[(size_t)(row0 + i) * N + col] = f2fp8(acc[r][c][i] * mul + bv);
      }
    }
  }
}
#undef GLDS

// ---- aggregation (fp8 g in): h = relu(sum g[c]/G_SCALE + b) -> fp8 x ACT ----
__global__ __launch_bounds__(256) void aggr_f8out(
    const unsigned char* __restrict__ g, const int* __restrict__ starts,
    const int* __restrict__ adj, const float* __restrict__ bias,
    unsigned char* __restrict__ hout) {
  const int node = blockIdx.y;
  const int f0 = blockIdx.x * 2048 + threadIdx.x * 8;
  float acc[8] = {0, 0, 0, 0, 0, 0, 0, 0};
  const int s = starts[node], e = starts[node + 1];
  int j = s;
  for (; j + 4 <= e; j += 4) {
    const int c0 = adj[j], c1 = adj[j + 1], c2 = adj[j + 2], c3 = adj[j + 3];
    int2 v0 = *(const int2*)(g + (size_t)c0 * HID_ + f0);
    int2 v1 = *(const int2*)(g + (size_t)c1 * HID_ + f0);
    int2 v2 = *(const int2*)(g + (size_t)c2 * HID_ + f0);
    int2 v3 = *(const int2*)(g + (size_t)c3 * HID_ + f0);
    fp8x4_acc(v0.x, acc);     fp8x4_acc(v0.y, acc + 4);
    fp8x4_acc(v1.x, acc);     fp8x4_acc(v1.y, acc + 4);
    fp8x4_acc(v2.x, acc);     fp8x4_acc(v2.y, acc + 4);
    fp8x4_acc(v3.x, acc);     fp8x4_acc(v3.y, acc + 4);
  }
  for (; j < e; ++j) {
    int2 v = *(const int2*)(g + (size_t)adj[j] * HID_ + f0);
    fp8x4_acc(v.x, acc);      fp8x4_acc(v.y, acc + 4);
  }
  const float4 b0 = *(const float4*)(bias + f0);
  const float4 b1 = *(const float4*)(bias + f0 + 4);
  const float bb[8] = {b0.x, b0.y, b0.z, b0.w, b1.x, b1.y, b1.z, b1.w};
  float v[8];
#pragma unroll
  for (int i = 0; i < 8; ++i)
    v[i] = ACT_SCALE * fmaxf(acc[i] * (1.0f / G_SCALE) + bb[i], 0.0f);
  int w0 = __builtin_amdgcn_cvt_pk_fp8_f32(v[0], v[1], 0, false);
  w0 = __builtin_amdgcn_cvt_pk_fp8_f32(v[2], v[3], w0, true);
  int w1 = __builtin_amdgcn_cvt_pk_fp8_f32(v[4], v[5], 0, false);
  w1 = __builtin_amdgcn_cvt_pk_fp8_f32(v[6], v[7], w1, true);
  *(int2*)(hout + (size_t)node * HID_ + f0) = make_int2(w0, w1);
}

// ---- fused final aggregation + row mean: hm[node] += sum_f relu(.)/HID ----
// (h2 never materialized: saves 33 MB write + 33 MB read + a launch)
__global__ __launch_bounds__(256) void aggr_mean(
    const unsigned char* __restrict__ g, const int* __restrict__ starts,
    const int* __restrict__ adj, const float* __restrict__ bias,
    float* __restrict__ hm) {
  const int node = blockIdx.y;
  const int f0 = blockIdx.x * 2048 + threadIdx.x * 8;
  float acc[8] = {0, 0, 0, 0, 0, 0, 0, 0};
  const int s = starts[node], e = starts[node + 1];
  int j = s;
  for (; j + 4 <= e; j += 4) {
    const int c0 = adj[j], c1 = adj[j + 1], c2 = adj[j + 2], c3 = adj[j + 3];
    int2 v0 = *(const int2*)(g + (size_t)c0 * HID_ + f0);
    int2 v1 = *(const int2*)(g + (size_t)c1 * HID_ + f0);
    int2 v2 = *(const int2*)(g + (size_t)c2 * HID_ + f0);
    int2 v3 = *(const int2*)(g + (size_t)c3 * HID_ + f0);
    fp8x4_acc(v0.x, acc);     fp8x4_acc(v0.y, acc + 4);
    fp8x4_acc(v1.x, acc);     fp8x4_acc(v1.y, acc + 4);
    fp8x4_acc(v2.x, acc);     fp8x4_acc(v2.y, acc + 4);
    fp8x4_acc(v3.x, acc);     fp8x4_acc(v3.y, acc + 4);
  }
  for (; j < e; ++j) {
    int2 v = *(const int2*)(g + (size_t)adj[j] * HID_ + f0);
    fp8x4_acc(v.x, acc);      fp8x4_acc(v.y, acc + 4);
  }
  const int t = threadIdx.x;
  const float4 b0 = *(const float4*)(bias + f0);
  const float4 b1 = *(const float4*)(bias + f0 + 4);
  const float bb[8] = {b0.x, b0.y, b0.z, b0.w, b1.x, b1.y, b1.z, b1.w};
  float local = 0.f;
#pragma unroll
  for (int i = 0; i < 8; ++i)
    local += fmaxf(acc[i] * (1.0f / G_SCALE) + bb[i], 0.0f);
  for (int off = 32; off > 0; off >>= 1) local += __shfl_down(local, off);
  __shared__ float ws[4];
  if ((t & 63) == 0) ws[t >> 6] = local;
  __syncthreads();
  if (t == 0)
    atomicAdd(&hm[node], (ws[0] + ws[1] + ws[2] + ws[3]) * (1.0f / (float)HID_));
}

// ---------------- z[j] = relu(Wc1[j,:].hm + bc1[j]), one wave per j ----------------
__global__ __launch_bounds__(256) void clf1(const float* __restrict__ Wc1,
                                            const float* __restrict__ bc1,
                                            const float* __restrict__ hm,
                                            float* __restrict__ z) {
  const int wave = threadIdx.x >> 6, lane = threadIdx.x & 63;
  const int j = blockIdx.x * 4 + wave;
  const float* w = Wc1 + (size_t)j * HID_;
  float s = 0.f;
  for (int i = lane; i < HID_; i += 64) s += w[i] * hm[i];
  for (int off = 32; off > 0; off >>= 1) s += __shfl_down(s, off);
  if (lane == 0) z[j] = fmaxf(s + bc1[j], 0.0f);
}

// ---------------- out = Wc2.z + bc2 ----------------
__global__ __launch_bounds__(256) void clf2(const float* __restrict__ Wc2,
                                            const float* __restrict__ bc2,
                                            const float* __restrict__ z,
                                            float* __restrict__ out) {
  const int t = threadIdx.x;
  float s = 0.f;
  for (int i = t; i < HID_ / 2; i += 256) s += z[i] * Wc2[i];
  for (int off = 32; off > 0; off >>= 1) s += __shfl_down(s, off);
  __shared__ float ws[4];
  if ((t & 63) == 0) ws[t >> 6] = s;
  __syncthreads();
  if (t == 0) out[0] = ws[0] + ws[1] + ws[2] + ws[3] + bc2[0];
}

extern "C" void kernel_launch(void* const* d_in, const int* in_sizes, int n_in,
                              void* d_out, int out_size, void* d_ws, size_t ws_size,
                              hipStream_t stream) {
  (void)in_sizes; (void)n_in; (void)out_size; (void)ws_size;
  const float* x       = (const float*)d_in[0];
  const int*   edge    = (const int*)d_in[1];
  const int*   row     = edge;
  const int*   col     = edge + NEDGE;
  const float* W_embed = (const float*)d_in[2];
  const float* b_embed = (const float*)d_in[3];
  const float* W1      = (const float*)d_in[4];
  const float* b1      = (const float*)d_in[5];
  const float* W2      = (const float*)d_in[6];
  const float* b2      = (const float*)d_in[7];
  const float* Wc1     = (const float*)d_in[8];
  const float* bc1     = (const float*)d_in[9];
  const float* Wc2     = (const float*)d_in[10];
  const float* bc2     = (const float*)d_in[11];
  float* out = (float*)d_out;

  char* ws = (char*)d_ws;
  size_t off = 0;
  auto alloc = [&](size_t bytes) {
    char* p = ws + off;
    off += (bytes + 255) & ~(size_t)255;
    return p;
  };
  unsigned char*  xf8  = (unsigned char*)alloc((size_t)N_NODES * IN_DIM_);
  unsigned char*  wef8 = (unsigned char*)alloc((size_t)HID_ * IN_DIM_);
  unsigned char*  w1f8 = (unsigned char*)alloc((size_t)HID_ * HID_);
  unsigned char*  w2f8 = (unsigned char*)alloc((size_t)HID_ * HID_);
  unsigned char*  h0f8 = (unsigned char*)alloc((size_t)N_NODES * HID_);
  unsigned char*  h1f8 = (unsigned char*)alloc((size_t)N_NODES * HID_);
  unsigned char*  g    = (unsigned char*)alloc((size_t)N_NODES * HID_);
  // counts | cursor | hm are allocated adjacently (each 16 KB, 256-aligned)
  // so one zero_i32 pass covers all three.
  int*   counts = (int*)alloc(N_NODES * 4);
  int*   cursor = (int*)alloc(N_NODES * 4);
  float* hm     = (float*)alloc(N_NODES * 4);
  int*   starts = (int*)alloc((N_NODES + 1) * 4);
  int*   adj    = (int*)alloc(NEDGE * 4);
  float* z      = (float*)alloc((HID_ / 2) * 4);

  // CSR build (ws is re-poisoned each call -> must zero). counts+cursor+hm
  // zeroed in ONE launch (12288 contiguous i32; 0x0 == 0.0f for hm).
  zero_i32<<<48, 256, 0, stream>>>(counts, 3 * N_NODES);
  hist_rows<<<NEDGE / 256, 256, 0, stream>>>(row, counts);
  scan4096<<<1, 1024, 0, stream>>>(counts, starts);
  fill_adj<<<NEDGE / 256, 256, 0, stream>>>(row, col, starts, cursor, adj);

  // all fp8 conversions in one launch (range dispatch; ranges are
  // multiples of one block's 2048 elems)
  cvt_all<<<(int)(CVT_E3 / 2048), 256, 0, stream>>>(x, W_embed, W1, W2,
                                                    xf8, wef8, w1f8, w2f8);

  // embed: h0 = fp8(8 * (x @ We^T + be))
  gemm_mx<<<256, 512, 0, stream>>>(xf8, wef8, h0f8, HID_, IN_DIM_,
                                   b_embed, G_STORE_MUL);
  // layer 1: g = h0 @ W1^T ; h1 = fp8(8 * relu(A g + b1))
  gemm_mx<<<256, 512, 0, stream>>>(h0f8, w1f8, g, HID_, HID_,
                                   nullptr, G_STORE_MUL);
  aggr_f8out<<<dim3(2, N_NODES), 256, 0, stream>>>(g, starts, adj, b1, h1f8);
  // layer 2: g = h1 @ W2^T ; hm[node] = mean_f relu(A g + b2) (fused)
  gemm_mx<<<256, 512, 0, stream>>>(h1f8, w2f8, g, HID_, HID_,
                                   nullptr, G_STORE_MUL);
  aggr_mean<<<dim3(2, N_NODES), 256, 0, stream>>>(g, starts, adj, b2, hm);
  // classifier tail
  clf1<<<(HID_ / 2) / 4, 256, 0, stream>>>(Wc1, bc1, hm, z);
  clf2<<<1, 256, 0, stream>>>(Wc2, bc2, z, out);
}

// Round 6
// 436.768 us; speedup vs baseline: 1.1380x; 1.0169x over previous
//
#include <hip/hip_runtime.h>
#include <hip/hip_bf16.h>

// GNN: h = x@We^T + be; 2x { h = relu(segsum(h[col],row) @ W^T + b) };
// out = relu(mean(h,1) @ Wc1^T + bc1) @ Wc2^T + bc2   (scalar fp32)
//
// Restructure: relu((A h) W^T + b) == relu(A (h W^T) + b)  (A = sparse adj).
// R12: XCD-slab the aggregation gathers. Old aggr (blockIdx.y=node) made
// every XCD stream all 16.7 MB of g through its private 4 MB L2 -> the
// 16x neighbor re-read (268 MB) was L3-served (~65 us/aggr est.). Now one
// wave per (node, 512-feature slab), linear block id b = node*8 + slab;
// with round-robin dispatch xcd = b&7 = slab, so each XCD touches only
// g[:, slab*512:+512] = 2 MB -> L2-resident; gathers run at L2 BW.
// Correctness is mapping-independent (slab assignment is a speed hint).
// R11: aggr_bf16out+row_mean fused (h2 never materialized, -66 MB);
// 4x cvt -> cvt_all; 1 zero pass. R10 LESSON: 12 live i32x8 frags +
// 128-reg acc spills to scratch (WRITE_SIZE +6 MB) -- keep R9's af reload.
// GEMM (R9, 74.6 us, MfmaUtil 37%): 1 barrier per K-tile; reads+staging
// upfront, compiler-counted lgkmcnt pipelines reads under MFMAs; boundary
// vmcnt(0) covered by a full tile of MFMA. SQ_LDS_BANK_CONFLICT == 4x
// ds_read_b128 count (intrinsic b128 overhead, m134), NOT a conflict.
//   - 256x256 tile, 512 threads, 8 waves (2Mx4N), BK=128, double-buffered
//     LDS (128 KiB), MX-scaled fp8 mfma_scale_f32_16x16x128_f8f6f4.
//   - LDS: natural 128B row stride, slot-XOR swizzle (16B slot ^= row&7);
//     inverse swizzle folded into per-lane GLOBAL source addresses of
//     global_load_lds (linear LDS dest), swizzled ds_read offsets.
//   - XCD swizzle: 4x8 sub-rectangle of tiles per XCD (12 MB panel set).

#define N_NODES 4096
#define IN_DIM_ 512
#define HID_ 4096
#define NEDGE 65536

typedef float f32x4 __attribute__((ext_vector_type(4)));
typedef float f32x2 __attribute__((ext_vector_type(2)));
typedef unsigned short u16x8 __attribute__((ext_vector_type(8)));
typedef int i32x8 __attribute__((ext_vector_type(8)));

#define ACT_SCALE 8.0f     // activations fp8 = 8 x true
#define W_SCALE 256.0f     // weights fp8 = 256 x true
#define G_SCALE 8.0f       // g fp8 = 8 x true
// gemm acc = 2048 x true; fp8-store multiplier = 8/2048
#define G_STORE_MUL (8.0f / 2048.0f)

__device__ __forceinline__ unsigned short f2bf(float f) {
  unsigned u = __float_as_uint(f);
  return (unsigned short)((u + 0x7fffu + ((u >> 16) & 1u)) >> 16);  // RNE
}
__device__ __forceinline__ float bf2f(unsigned short h) {
  return __uint_as_float((unsigned)h << 16);
}
__device__ __forceinline__ unsigned char f2fp8(float f) {
  int w = __builtin_amdgcn_cvt_pk_fp8_f32(f, f, 0, false);  // OCP e4m3
  return (unsigned char)(w & 0xff);
}
// decode 4 fp8 bytes of w into acc[0..3] (+=)
__device__ __forceinline__ void fp8x4_acc(int w, float* acc) {
  f32x2 lo = __builtin_amdgcn_cvt_pk_f32_fp8(w, false);
  f32x2 hi = __builtin_amdgcn_cvt_pk_f32_fp8(w, true);
  acc[0] += lo[0]; acc[1] += lo[1]; acc[2] += hi[0]; acc[3] += hi[1];
}

// ------- fused fp32 -> fp8 e4m3 for x|We|W1|W2 (range dispatch) -------
#define CVT_E0 ((long)N_NODES * IN_DIM_)                  // x:  2097152
#define CVT_E1 (CVT_E0 + (long)HID_ * IN_DIM_)            // We: 4194304
#define CVT_E2 (CVT_E1 + (long)HID_ * HID_)               // W1: 20971520
#define CVT_E3 (CVT_E2 + (long)HID_ * HID_)               // W2: 37748736
__global__ __launch_bounds__(256) void cvt_all(
    const float* __restrict__ x, const float* __restrict__ We,
    const float* __restrict__ W1, const float* __restrict__ W2,
    unsigned char* __restrict__ xf8, unsigned char* __restrict__ wef8,
    unsigned char* __restrict__ w1f8, unsigned char* __restrict__ w2f8) {
  long i = ((long)blockIdx.x * 256 + threadIdx.x) * 8;
  const float* src; unsigned char* dst; float sc; long o;
  if (i < CVT_E0)      { src = x;  dst = xf8;  sc = ACT_SCALE; o = i; }
  else if (i < CVT_E1) { src = We; dst = wef8; sc = W_SCALE; o = i - CVT_E0; }
  else if (i < CVT_E2) { src = W1; dst = w1f8; sc = W_SCALE; o = i - CVT_E1; }
  else                 { src = W2; dst = w2f8; sc = W_SCALE; o = i - CVT_E2; }
  const float4 a = *(const float4*)(src + o);
  const float4 b = *(const float4*)(src + o + 4);
  int w0 = __builtin_amdgcn_cvt_pk_fp8_f32(a.x * sc, a.y * sc, 0, false);
  w0 = __builtin_amdgcn_cvt_pk_fp8_f32(a.z * sc, a.w * sc, w0, true);
  int w1 = __builtin_amdgcn_cvt_pk_fp8_f32(b.x * sc, b.y * sc, 0, false);
  w1 = __builtin_amdgcn_cvt_pk_fp8_f32(b.z * sc, b.w * sc, w1, true);
  *(int2*)(dst + o) = make_int2(w0, w1);
}

// ---------------- CSR build ----------------
__global__ __launch_bounds__(256) void zero_i32(int* __restrict__ p, int n) {
  int i = blockIdx.x * 256 + threadIdx.x;
  if (i < n) p[i] = 0;
}

__global__ __launch_bounds__(256) void hist_rows(const int* __restrict__ row,
                                                 int* __restrict__ counts) {
  int e = blockIdx.x * 256 + threadIdx.x;
  if (e < NEDGE) atomicAdd(&counts[row[e]], 1);
}

// exclusive scan of counts[4096] -> starts[4097]; single block of 1024 threads
__global__ __launch_bounds__(1024) void scan4096(const int* __restrict__ counts,
                                                 int* __restrict__ starts) {
  __shared__ int sa[1024], sb[1024];
  const int t = threadIdx.x;
  const int c0 = counts[t * 4], c1 = counts[t * 4 + 1],
            c2 = counts[t * 4 + 2], c3 = counts[t * 4 + 3];
  const int local = c0 + c1 + c2 + c3;
  sa[t] = local;
  __syncthreads();
  int* src = sa; int* dst = sb;
  for (int off = 1; off < 1024; off <<= 1) {
    int v = src[t];
    if (t >= off) v += src[t - off];
    dst[t] = v;
    __syncthreads();
    int* tmp = src; src = dst; dst = tmp;
  }
  const int excl = (t == 0) ? 0 : src[t - 1];
  starts[t * 4]     = excl;
  starts[t * 4 + 1] = excl + c0;
  starts[t * 4 + 2] = excl + c0 + c1;
  starts[t * 4 + 3] = excl + c0 + c1 + c2;
  if (t == 1023) starts[4096] = excl + local;
}

__global__ __launch_bounds__(256) void fill_adj(const int* __restrict__ row,
                                                const int* __restrict__ col,
                                                const int* __restrict__ starts,
                                                int* __restrict__ cursor,
                                                int* __restrict__ adj) {
  int e = blockIdx.x * 256 + threadIdx.x;
  if (e >= NEDGE) return;
  int r = row[e];
  int p = atomicAdd(&cursor[r], 1);
  adj[starts[r] + p] = col[e];
}

// ---- MX fp8 GEMM: C_fp8 = fp8(mul*(A@B^T) [+ ACT_SCALE*bias]) ----
// 256x256 tile, BK=128, 8 waves each 128x64, 1 barrier per K-tile. (R9)
#define GLDS(gp, lp)                                                       \
  __builtin_amdgcn_global_load_lds(                                        \
      (const __attribute__((address_space(1))) void*)(gp),                 \
      (__attribute__((address_space(3))) void*)(lp), 16, 0, 0)

__global__ __launch_bounds__(512, 2) void gemm_mx(
    const unsigned char* __restrict__ A, const unsigned char* __restrict__ B,
    unsigned char* __restrict__ C, int N, int K,
    const float* __restrict__ bias, float mul) {
  __shared__ unsigned char lds[131072];   // [A dbuf 2x32K][B dbuf 2x32K]
  const int t = threadIdx.x;
  // XCD swizzle: XCD x owns a 4(bm) x 8(bn) sub-rectangle of the 16x16 tile
  // grid (bijective for nwg=256). 32 co-resident blocks/XCD share
  // 4 A-panels + 8 B-panels; per-K-step working set 384 KB << 4 MB L2.
  const int w = blockIdx.x;
  const int xcd = w & 7, j = w >> 3;
  const int bm = ((xcd & 3) * 4 + (j & 3)) * 256;
  const int bn = ((xcd >> 2) * 8 + (j >> 2)) * 256;
  const int wave = t >> 6, lane = t & 63;
  const int wm = (wave >> 2) * 128, wn = (wave & 3) * 64;
  const int m16 = lane & 15, quad = lane >> 4;

  f32x4 acc[8][4] = {};

  // staging: thread t, inst i -> LDS linear byte (i*64 + t/8)*128 + (t%8)*16.
  // LDS slot s of row r must hold global k-slot s^(r&7)  (read-side swizzle),
  // so pre-XOR the per-lane GLOBAL source slot; LDS dest stays linear.
  const int rS = t >> 3;                       // 0..63
  const int sS = ((t & 7) ^ (rS & 7)) << 4;    // pre-swizzled k-slot byte
  const unsigned char* Ag = A + (size_t)(bm + rS) * K + sS;
  const unsigned char* Bg = B + (size_t)(bn + rS) * K + sS;
  const size_t rstep = (size_t)64 * K;         // +64 rows per staging inst
  unsigned char* Als = lds;
  unsigned char* Bls = lds + 65536;
  const int sd = t * 16;

  // read-side swizzled 16B-slot offsets for k = quad*32 .. +31
  const int o0 = ((quad << 1) ^ (lane & 7)) << 4;
  const int o1 = o0 ^ 16;

  const int KT = K >> 7;

#define STAGE_A(i, kb, dst) GLDS(Ag + (kb) + (size_t)(i) * rstep, (dst) + (i) * 8192 + sd)
#define STAGE_B(i, kb, dst) GLDS(Bg + (kb) + (size_t)(i) * rstep, (dst) + (i) * 8192 + sd)

#define LDFRAG(dst, base, row)                                             \
  {                                                                        \
    const unsigned char* _p = (base) + (row) * 128;                        \
    const int4 _lo = *(const int4*)(_p + o0);                              \
    const int4 _hi = *(const int4*)(_p + o1);                              \
    dst[0] = _lo.x; dst[1] = _lo.y; dst[2] = _lo.z; dst[3] = _lo.w;        \
    dst[4] = _hi.x; dst[5] = _hi.y; dst[6] = _hi.z; dst[7] = _hi.w;        \
  }

#define MFMA(r, c, afr, bfr)                                               \
  acc[r][c] = __builtin_amdgcn_mfma_scale_f32_16x16x128_f8f6f4(            \
      afr, bfr, acc[r][c], 0, 0, 0, 0x7f7f7f7f, 0, 0x7f7f7f7f)

  // prologue: stage tile 0 into buf 0 (only exposed wait of the loop)
  STAGE_A(0, 0, Als); STAGE_A(1, 0, Als); STAGE_A(2, 0, Als); STAGE_A(3, 0, Als);
  STAGE_B(0, 0, Bls); STAGE_B(1, 0, Bls); STAGE_B(2, 0, Bls); STAGE_B(3, 0, Bls);
  asm volatile("s_waitcnt vmcnt(0)" ::: "memory");
  __builtin_amdgcn_s_barrier();

  i32x8 af[4], bf01[2], bf23[2];

  for (int tt = 0; tt < KT; ++tt) {
    unsigned char* Ab = Als + (tt & 1) * 32768;
    unsigned char* Bb = Bls + (tt & 1) * 32768;
    unsigned char* An = Als + ((tt + 1) & 1) * 32768;
    unsigned char* Bn = Bls + ((tt + 1) & 1) * 32768;
    const int kbn = (tt + 1) << 7;
    const bool more = (tt + 1) < KT;

    // Issue all M0-3 + B fragment reads (16 ds_read in flight), then the
    // next-tile A staging; MFMA clusters follow with compiler-counted
    // lgkmcnt waits -- reads for later clusters stay in flight under
    // earlier clusters' MFMAs. No intra-tile barriers: buf-cur reads and
    // buf-nxt staging writes cannot collide.
    LDFRAG(af[0], Ab, wm + m16);
    LDFRAG(af[1], Ab, wm + 16 + m16);
    LDFRAG(af[2], Ab, wm + 32 + m16);
    LDFRAG(af[3], Ab, wm + 48 + m16);
    LDFRAG(bf01[0], Bb, wn + m16);
    LDFRAG(bf01[1], Bb, wn + 16 + m16);
    LDFRAG(bf23[0], Bb, wn + 32 + m16);
    LDFRAG(bf23[1], Bb, wn + 48 + m16);
    if (more) {
      STAGE_A(0, kbn, An); STAGE_A(1, kbn, An);
      STAGE_A(2, kbn, An); STAGE_A(3, kbn, An);
    }
    __builtin_amdgcn_s_setprio(1);
    MFMA(0, 0, af[0], bf01[0]); MFMA(0, 1, af[0], bf01[1]);
    MFMA(1, 0, af[1], bf01[0]); MFMA(1, 1, af[1], bf01[1]);
    MFMA(2, 0, af[2], bf01[0]); MFMA(2, 1, af[2], bf01[1]);
    MFMA(3, 0, af[3], bf01[0]); MFMA(3, 1, af[3], bf01[1]);
    __builtin_amdgcn_s_setprio(0);
    if (more) {
      STAGE_B(0, kbn, Bn); STAGE_B(1, kbn, Bn);
      STAGE_B(2, kbn, Bn); STAGE_B(3, kbn, Bn);
    }
    __builtin_amdgcn_s_setprio(1);
    MFMA(0, 2, af[0], bf23[0]); MFMA(0, 3, af[0], bf23[1]);
    MFMA(1, 2, af[1], bf23[0]); MFMA(1, 3, af[1], bf23[1]);
    MFMA(2, 2, af[2], bf23[0]); MFMA(2, 3, af[2], bf23[1]);
    MFMA(3, 2, af[3], bf23[0]); MFMA(3, 3, af[3], bf23[1]);
    __builtin_amdgcn_s_setprio(0);
    // reload af with rows M4-7 (WAR on af: HW scoreboard orders the LDS
    // writeback after the consuming MFMAs read their operands)
    LDFRAG(af[0], Ab, wm + 64 + m16);
    LDFRAG(af[1], Ab, wm + 80 + m16);
    LDFRAG(af[2], Ab, wm + 96 + m16);
    LDFRAG(af[3], Ab, wm + 112 + m16);
    __builtin_amdgcn_s_setprio(1);
    MFMA(4, 0, af[0], bf01[0]); MFMA(4, 1, af[0], bf01[1]);
    MFMA(5, 0, af[1], bf01[0]); MFMA(5, 1, af[1], bf01[1]);
    MFMA(6, 0, af[2], bf01[0]); MFMA(6, 1, af[2], bf01[1]);
    MFMA(7, 0, af[3], bf01[0]); MFMA(7, 1, af[3], bf01[1]);
    __builtin_amdgcn_s_setprio(0);
    __builtin_amdgcn_s_setprio(1);
    MFMA(4, 2, af[0], bf23[0]); MFMA(4, 3, af[0], bf23[1]);
    MFMA(5, 2, af[1], bf23[0]); MFMA(5, 3, af[1], bf23[1]);
    MFMA(6, 2, af[2], bf23[0]); MFMA(6, 3, af[2], bf23[1]);
    MFMA(7, 2, af[3], bf23[0]); MFMA(7, 3, af[3], bf23[1]);
    __builtin_amdgcn_s_setprio(0);
    if (more) {
      // tile-boundary: t+1's staging (issued ~1-2k cyc ago) must have
      // landed, and all waves' buf-cur reads are drained (every read was
      // consumed by an MFMA above). The loop's ONLY barrier.
      asm volatile("s_waitcnt vmcnt(0)" ::: "memory");
      __builtin_amdgcn_sched_barrier(0);
      __builtin_amdgcn_s_barrier();
    }
  }

#undef MFMA
#undef LDFRAG
#undef STAGE_A
#undef STAGE_B

  // C/D layout (16x16 family, shape-determined): col=lane&15, row=quad*4+reg
#pragma unroll
  for (int r = 0; r < 8; ++r) {
#pragma unroll
    for (int c = 0; c < 4; ++c) {
      const int row0 = bm + wm + r * 16 + quad * 4;
      const int col = bn + wn + c * 16 + m16;
      const float bv = bias ? ACT_SCALE * bias[col] : 0.0f;
#pragma unroll
      for (int i = 0; i < 4; ++i) {
        C[(size_t)(row0 + i) * N + col] = f2fp8(acc[r][c][i] * mul + bv);
      }
    }
  }
}
#undef GLDS

// ---- aggregation (fp8 g in): h = relu(sum g[c]/G_SCALE + b) -> fp8 x ACT ----
// One wave per (node, 512-feature slab). Linear block id b = node*8 + slab;
// round-robin dispatch -> xcd = b&7 = slab, so each XCD's gathers touch only
// g[:, slab*512:+512] (2 MB, L2-resident). Mapping is a speed hint only.
__global__ __launch_bounds__(64) void aggr_f8out(
    const unsigned char* __restrict__ g, const int* __restrict__ starts,
    const int* __restrict__ adj, const float* __restrict__ bias,
    unsigned char* __restrict__ hout) {
  const int node = blockIdx.x >> 3;
  const int f0 = (blockIdx.x & 7) * 512 + threadIdx.x * 8;
  float acc[8] = {0, 0, 0, 0, 0, 0, 0, 0};
  const int s = starts[node], e = starts[node + 1];
  int j = s;
  for (; j + 4 <= e; j += 4) {
    const int c0 = adj[j], c1 = adj[j + 1], c2 = adj[j + 2], c3 = adj[j + 3];
    int2 v0 = *(const int2*)(g + (size_t)c0 * HID_ + f0);
    int2 v1 = *(const int2*)(g + (size_t)c1 * HID_ + f0);
    int2 v2 = *(const int2*)(g + (size_t)c2 * HID_ + f0);
    int2 v3 = *(const int2*)(g + (size_t)c3 * HID_ + f0);
    fp8x4_acc(v0.x, acc);     fp8x4_acc(v0.y, acc + 4);
    fp8x4_acc(v1.x, acc);     fp8x4_acc(v1.y, acc + 4);
    fp8x4_acc(v2.x, acc);     fp8x4_acc(v2.y, acc + 4);
    fp8x4_acc(v3.x, acc);     fp8x4_acc(v3.y, acc + 4);
  }
  for (; j < e; ++j) {
    int2 v = *(const int2*)(g + (size_t)adj[j] * HID_ + f0);
    fp8x4_acc(v.x, acc);      fp8x4_acc(v.y, acc + 4);
  }
  const float4 b0 = *(const float4*)(bias + f0);
  const float4 b1 = *(const float4*)(bias + f0 + 4);
  const float bb[8] = {b0.x, b0.y, b0.z, b0.w, b1.x, b1.y, b1.z, b1.w};
  float v[8];
#pragma unroll
  for (int i = 0; i < 8; ++i)
    v[i] = ACT_SCALE * fmaxf(acc[i] * (1.0f / G_SCALE) + bb[i], 0.0f);
  int w0 = __builtin_amdgcn_cvt_pk_fp8_f32(v[0], v[1], 0, false);
  w0 = __builtin_amdgcn_cvt_pk_fp8_f32(v[2], v[3], w0, true);
  int w1 = __builtin_amdgcn_cvt_pk_fp8_f32(v[4], v[5], 0, false);
  w1 = __builtin_amdgcn_cvt_pk_fp8_f32(v[6], v[7], w1, true);
  *(int2*)(hout + (size_t)node * HID_ + f0) = make_int2(w0, w1);
}

// ---- fused final aggregation + row mean: hm[node] += sum_f relu(.)/HID ----
// (h2 never materialized; same XCD-slab structure as aggr_f8out)
__global__ __launch_bounds__(64) void aggr_mean(
    const unsigned char* __restrict__ g, const int* __restrict__ starts,
    const int* __restrict__ adj, const float* __restrict__ bias,
    float* __restrict__ hm) {
  const int node = blockIdx.x >> 3;
  const int f0 = (blockIdx.x & 7) * 512 + threadIdx.x * 8;
  float acc[8] = {0, 0, 0, 0, 0, 0, 0, 0};
  const int s = starts[node], e = starts[node + 1];
  int j = s;
  for (; j + 4 <= e; j += 4) {
    const int c0 = adj[j], c1 = adj[j + 1], c2 = adj[j + 2], c3 = adj[j + 3];
    int2 v0 = *(const int2*)(g + (size_t)c0 * HID_ + f0);
    int2 v1 = *(const int2*)(g + (size_t)c1 * HID_ + f0);
    int2 v2 = *(const int2*)(g + (size_t)c2 * HID_ + f0);
    int2 v3 = *(const int2*)(g + (size_t)c3 * HID_ + f0);
    fp8x4_acc(v0.x, acc);     fp8x4_acc(v0.y, acc + 4);
    fp8x4_acc(v1.x, acc);     fp8x4_acc(v1.y, acc + 4);
    fp8x4_acc(v2.x, acc);     fp8x4_acc(v2.y, acc + 4);
    fp8x4_acc(v3.x, acc);     fp8x4_acc(v3.y, acc + 4);
  }
  for (; j < e; ++j) {
    int2 v = *(const int2*)(g + (size_t)adj[j] * HID_ + f0);
    fp8x4_acc(v.x, acc);      fp8x4_acc(v.y, acc + 4);
  }
  const float4 b0 = *(const float4*)(bias + f0);
  const float4 b1 = *(const float4*)(bias + f0 + 4);
  const float bb[8] = {b0.x, b0.y, b0.z, b0.w, b1.x, b1.y, b1.z, b1.w};
  float local = 0.f;
#pragma unroll
  for (int i = 0; i < 8; ++i)
    local += fmaxf(acc[i] * (1.0f / G_SCALE) + bb[i], 0.0f);
  for (int off = 32; off > 0; off >>= 1) local += __shfl_down(local, off);
  if (threadIdx.x == 0)
    atomicAdd(&hm[node], local * (1.0f / (float)HID_));
}

// ---------------- z[j] = relu(Wc1[j,:].hm + bc1[j]), one wave per j ----------------
__global__ __launch_bounds__(256) void clf1(const float* __restrict__ Wc1,
                                            const float* __restrict__ bc1,
                                            const float* __restrict__ hm,
                                            float* __restrict__ z) {
  const int wave = threadIdx.x >> 6, lane = threadIdx.x & 63;
  const int j = blockIdx.x * 4 + wave;
  const float* w = Wc1 + (size_t)j * HID_;
  float s = 0.f;
  for (int i = lane; i < HID_; i += 64) s += w[i] * hm[i];
  for (int off = 32; off > 0; off >>= 1) s += __shfl_down(s, off);
  if (lane == 0) z[j] = fmaxf(s + bc1[j], 0.0f);
}

// ---------------- out = Wc2.z + bc2 ----------------
__global__ __launch_bounds__(256) void clf2(const float* __restrict__ Wc2,
                                            const float* __restrict__ bc2,
                                            const float* __restrict__ z,
                                            float* __restrict__ out) {
  const int t = threadIdx.x;
  float s = 0.f;
  for (int i = t; i < HID_ / 2; i += 256) s += z[i] * Wc2[i];
  for (int off = 32; off > 0; off >>= 1) s += __shfl_down(s, off);
  __shared__ float ws[4];
  if ((t & 63) == 0) ws[t >> 6] = s;
  __syncthreads();
  if (t == 0) out[0] = ws[0] + ws[1] + ws[2] + ws[3] + bc2[0];
}

extern "C" void kernel_launch(void* const* d_in, const int* in_sizes, int n_in,
                              void* d_out, int out_size, void* d_ws, size_t ws_size,
                              hipStream_t stream) {
  (void)in_sizes; (void)n_in; (void)out_size; (void)ws_size;
  const float* x       = (const float*)d_in[0];
  const int*   edge    = (const int*)d_in[1];
  const int*   row     = edge;
  const int*   col     = edge + NEDGE;
  const float* W_embed = (const float*)d_in[2];
  const float* b_embed = (const float*)d_in[3];
  const float* W1      = (const float*)d_in[4];
  const float* b1      = (const float*)d_in[5];
  const float* W2      = (const float*)d_in[6];
  const float* b2      = (const float*)d_in[7];
  const float* Wc1     = (const float*)d_in[8];
  const float* bc1     = (const float*)d_in[9];
  const float* Wc2     = (const float*)d_in[10];
  const float* bc2     = (const float*)d_in[11];
  float* out = (float*)d_out;

  char* ws = (char*)d_ws;
  size_t off = 0;
  auto alloc = [&](size_t bytes) {
    char* p = ws + off;
    off += (bytes + 255) & ~(size_t)255;
    return p;
  };
  unsigned char*  xf8  = (unsigned char*)alloc((size_t)N_NODES * IN_DIM_);
  unsigned char*  wef8 = (unsigned char*)alloc((size_t)HID_ * IN_DIM_);
  unsigned char*  w1f8 = (unsigned char*)alloc((size_t)HID_ * HID_);
  unsigned char*  w2f8 = (unsigned char*)alloc((size_t)HID_ * HID_);
  unsigned char*  h0f8 = (unsigned char*)alloc((size_t)N_NODES * HID_);
  unsigned char*  h1f8 = (unsigned char*)alloc((size_t)N_NODES * HID_);
  unsigned char*  g    = (unsigned char*)alloc((size_t)N_NODES * HID_);
  // counts | cursor | hm are allocated adjacently (each 16 KB, 256-aligned)
  // so one zero_i32 pass covers all three.
  int*   counts = (int*)alloc(N_NODES * 4);
  int*   cursor = (int*)alloc(N_NODES * 4);
  float* hm     = (float*)alloc(N_NODES * 4);
  int*   starts = (int*)alloc((N_NODES + 1) * 4);
  int*   adj    = (int*)alloc(NEDGE * 4);
  float* z      = (float*)alloc((HID_ / 2) * 4);

  // CSR build (ws is re-poisoned each call -> must zero). counts+cursor+hm
  // zeroed in ONE launch (12288 contiguous i32; 0x0 == 0.0f for hm).
  zero_i32<<<48, 256, 0, stream>>>(counts, 3 * N_NODES);
  hist_rows<<<NEDGE / 256, 256, 0, stream>>>(row, counts);
  scan4096<<<1, 1024, 0, stream>>>(counts, starts);
  fill_adj<<<NEDGE / 256, 256, 0, stream>>>(row, col, starts, cursor, adj);

  // all fp8 conversions in one launch (range dispatch; ranges are
  // multiples of one block's 2048 elems)
  cvt_all<<<(int)(CVT_E3 / 2048), 256, 0, stream>>>(x, W_embed, W1, W2,
                                                    xf8, wef8, w1f8, w2f8);

  // embed: h0 = fp8(8 * (x @ We^T + be))
  gemm_mx<<<256, 512, 0, stream>>>(xf8, wef8, h0f8, HID_, IN_DIM_,
                                   b_embed, G_STORE_MUL);
  // layer 1: g = h0 @ W1^T ; h1 = fp8(8 * relu(A g + b1))
  gemm_mx<<<256, 512, 0, stream>>>(h0f8, w1f8, g, HID_, HID_,
                                   nullptr, G_STORE_MUL);
  aggr_f8out<<<N_NODES * 8, 64, 0, stream>>>(g, starts, adj, b1, h1f8);
  // layer 2: g = h1 @ W2^T ; hm[node] = mean_f relu(A g + b2) (fused)
  gemm_mx<<<256, 512, 0, stream>>>(h1f8, w2f8, g, HID_, HID_,
                                   nullptr, G_STORE_MUL);
  aggr_mean<<<N_NODES * 8, 64, 0, stream>>>(g, starts, adj, b2, hm);
  // classifier tail
  clf1<<<(HID_ / 2) / 4, 256, 0, stream>>>(Wc1, bc1, hm, z);
  clf2<<<1, 256, 0, stream>>>(Wc2, bc2, z, out);
}